// Round 4
// baseline (940.175 us; speedup 1.0000x reference)
//
#include <hip/hip_runtime.h>
#include <hip/hip_fp16.h>

#define N_NODES 100000
#define N_EDGES 3200000
#define F_IN    128
#define F_HID   32

#define BSHIFT  7
#define BKSZ    128                               // nodes per bucket
#define NBKT    ((N_NODES + BKSZ - 1) / BKSZ)     // 782
#define CAP     4608                              // bucket capacity: mean 4092 + 8 sigma
#define CHUNK   8192                              // edges per partition block
#define NBLK_E  ((N_EDGES + CHUNK - 1) / CHUNK)   // 391
#define RBITS   17                                // row id bits (100000 < 2^17)
#define RMASK   0x1FFFF

// ---------------- bucket partition (no global sort, no scan) ----------------

__global__ __launch_bounds__(256) void k_init(int* __restrict__ gcur) {
    int i = blockIdx.x * 256 + threadIdx.x;
    if (i < NBKT) gcur[i] = i * CAP;   // each bucket gets a fixed region
}

// partition edges into per-bucket regions; packed word = r | (c&127)<<17
__global__ __launch_bounds__(256) void k_part(const int* __restrict__ row, const int* __restrict__ col,
                                              int* __restrict__ gcur, unsigned* __restrict__ bkt) {
    __shared__ int hist[NBKT];
    __shared__ int base[NBKT];
    int t = threadIdx.x;
    for (int i = t; i < NBKT; i += 256) hist[i] = 0;
    __syncthreads();
    int e0 = blockIdx.x * CHUNK;
    int n  = min(CHUNK, N_EDGES - e0);
    for (int i = t; i < n; i += 256) atomicAdd(&hist[col[e0 + i] >> BSHIFT], 1);
    __syncthreads();
    for (int i = t; i < NBKT; i += 256) {
        int h = hist[i];
        base[i] = h ? atomicAdd(&gcur[i], h) : 0;
    }
    __syncthreads();
    for (int i = t; i < NBKT; i += 256) hist[i] = 0;
    __syncthreads();
    for (int i = t; i < n; i += 256) {
        int c = col[e0 + i];       // L2 hit (second read)
        int b = c >> BSHIFT;
        int p = base[b] + atomicAdd(&hist[b], 1);
        bkt[p] = (unsigned)row[e0 + i] | ((unsigned)(c & (BKSZ - 1)) << RBITS);
    }
}

// per-bucket degree -> dinv = rsqrt(deg+1)
__global__ __launch_bounds__(256) void k_deg(const unsigned* __restrict__ bkt, const int* __restrict__ gcur,
                                             float* __restrict__ dinv) {
    __shared__ int cnt[BKSZ];
    int t = threadIdx.x, b = blockIdx.x;
    if (t < BKSZ) cnt[t] = 0;
    __syncthreads();
    int s = b * CAP, e = gcur[b];
    for (int i = s + t; i < e; i += 256) atomicAdd(&cnt[bkt[i] >> RBITS], 1);
    __syncthreads();
    int g = (b << BSHIFT) + t;
    if (t < BKSZ && g < N_NODES) dinv[g] = rsqrtf((float)(cnt[t] + 1));
}

// ---------------- h1s = fp16( dinv[r] * (x @ W1)[r] ), packed 2 feats/thread ----------------

__global__ __launch_bounds__(256) void k_gemm1(const float* __restrict__ x, const float* __restrict__ W1,
                                               const float* __restrict__ dinv, unsigned* __restrict__ h1s) {
    __shared__ float Wlds[F_IN * F_HID];  // 16 KB, [k][f]
    int t = threadIdx.x;
    for (int i = t; i < F_IN * F_HID; i += 256) Wlds[i] = W1[i];
    __syncthreads();

    int gid = blockIdx.x * 256 + t;   // gid = r*16 + f2 ; feats 2*f2, 2*f2+1
    int r = gid >> 4, f2 = gid & 15;
    if (r >= N_NODES) return;

    const float4* x4 = (const float4*)(x + (size_t)r * F_IN);
    float a0 = 0.0f, a1 = 0.0f;
    int fa = 2 * f2, fb = 2 * f2 + 1;
#pragma unroll
    for (int k = 0; k < F_IN / 4; k++) {
        float4 xv = x4[k];
        a0 += xv.x * Wlds[(4 * k + 0) * F_HID + fa] + xv.y * Wlds[(4 * k + 1) * F_HID + fa]
            + xv.z * Wlds[(4 * k + 2) * F_HID + fa] + xv.w * Wlds[(4 * k + 3) * F_HID + fa];
        a1 += xv.x * Wlds[(4 * k + 0) * F_HID + fb] + xv.y * Wlds[(4 * k + 1) * F_HID + fb]
            + xv.z * Wlds[(4 * k + 2) * F_HID + fb] + xv.w * Wlds[(4 * k + 3) * F_HID + fb];
    }
    float di = dinv[r];
    unsigned s0 = (unsigned)__half_as_ushort(__float2half(di * a0));
    unsigned s1 = (unsigned)__half_as_ushort(__float2half(di * a1));
    h1s[gid] = s0 | (s1 << 16);
}

// ---------------- conv1: LDS-accumulate Σ h1s[r] per dest, then tanh+W2 epilogue ----------------
// h2s4[c*4+j] = dinv[c] * (tanh(...) @ W2)[j],  j<3 (slot 3 = 0)

__global__ __launch_bounds__(256) void k_conv1(const unsigned* __restrict__ bkt, const int* __restrict__ gcur,
                                               const float* __restrict__ dinv,
                                               const unsigned short* __restrict__ h1su,
                                               const float* __restrict__ W2, float* __restrict__ h2s4) {
    __shared__ float acc[BKSZ * F_HID];  // 16 KB
    int t = threadIdx.x, b = blockIdx.x;
    for (int i = t; i < BKSZ * F_HID; i += 256) acc[i] = 0.0f;

    int lane = t & 63, wid = t >> 6;
    int f = lane & 31;           // feature (== LDS bank: conflict-free ds_add)
    int h = lane >> 5;           // half-wave -> edge slot
    float w20 = W2[f * 3 + 0], w21 = W2[f * 3 + 1], w22 = W2[f * 3 + 2];
    __syncthreads();

    int s = b * CAP, e = gcur[b];
    // 8 edges per block-iter (4 waves x 2 half-waves)
    for (int p = s + wid * 2 + h; p < e; p += 8) {
        unsigned w = bkt[p];                    // broadcast within half-wave
        int r  = w & RMASK;
        int cl = w >> RBITS;
        float v = __half2float(__ushort_as_half(h1su[(size_t)r * F_HID + f]));  // 64B coalesced
        atomicAdd(&acc[cl * F_HID + f], v);     // ds_add_f32, bank f
    }
    __syncthreads();

    // epilogue: wave wid handles nodes [wid*32, wid*32+32), 2 nodes per pass
    for (int i = 0; i < 16; i++) {
        int n = wid * 32 + i * 2 + h;
        int g = (b << BSHIFT) + n;
        if (g >= N_NODES) continue;
        float di = dinv[g];
        float selfv = __half2float(__ushort_as_half(h1su[(size_t)g * F_HID + f]));
        float hid = tanhf(di * (acc[n * F_HID + f] + selfv));
        float p0 = hid * w20, p1 = hid * w21, p2 = hid * w22;
#pragma unroll
        for (int m = 1; m <= 16; m <<= 1) {  // reduce over f within 32-group
            p0 += __shfl_xor(p0, m);
            p1 += __shfl_xor(p1, m);
            p2 += __shfl_xor(p2, m);
        }
        if (f < 4) {
            float v = (f == 0) ? p0 : (f == 1) ? p1 : (f == 2) ? p2 : 0.0f;
            h2s4[(size_t)g * 4 + f] = di * v;
        }
    }
}

// ---------------- conv2: LDS-accumulate Σ h2s[r], epilogue writes out ----------------

__global__ __launch_bounds__(256) void k_conv2(const unsigned* __restrict__ bkt, const int* __restrict__ gcur,
                                               const float* __restrict__ dinv,
                                               const float* __restrict__ h2s4, float* __restrict__ out) {
    __shared__ float acc[BKSZ * 4];  // 2 KB
    int t = threadIdx.x, b = blockIdx.x;
    for (int i = t; i < BKSZ * 4; i += 256) acc[i] = 0.0f;
    __syncthreads();

    int lane = t & 63, wid = t >> 6;
    int tm = lane >> 2, j = lane & 3;   // 16 teams of 4 lanes per wave
    int s = b * CAP, e = gcur[b];
    for (int p = s + wid * 16 + tm; p < e; p += 64) {
        unsigned w = bkt[p];            // broadcast within team
        int r  = w & RMASK;
        int cl = w >> RBITS;
        if (j < 3) atomicAdd(&acc[cl * 4 + j], h2s4[(size_t)r * 4 + j]);
    }
    __syncthreads();

    if (t < BKSZ) {
        int g = (b << BSHIFT) + t;
        if (g < N_NODES) {
            float di = dinv[g];
#pragma unroll
            for (int jj = 0; jj < 3; jj++)
                out[(size_t)g * 3 + jj] = di * (acc[t * 4 + jj] + h2s4[(size_t)g * 4 + jj]);
        }
    }
}

// ---------------- launch ----------------

extern "C" void kernel_launch(void* const* d_in, const int* in_sizes, int n_in,
                              void* d_out, int out_size, void* d_ws, size_t ws_size,
                              hipStream_t stream) {
    const float* x   = (const float*)d_in[0];
    const int*   ei  = (const int*)d_in[1];  // [2, E] int32
    const float* W1  = (const float*)d_in[2];
    const float* W2  = (const float*)d_in[3];
    float*       out = (float*)d_out;

    const int* row = ei;
    const int* col = ei + N_EDGES;

    // workspace:
    //  bkt  : NBKT*CAP u32  = 14.42 MB
    //  gcur : NBKT int
    //  dinv : N float       = 0.40 MB
    //  h1s  : N*16 u32      = 6.40 MB  (fp16 x 32 feats, dinv-scaled)
    //  h2s4 : N*4  f32      = 1.60 MB  (dinv-scaled h2, padded to 16B)
    // total ~22.9 MB (< 27.6 MB proven in R3)
    char* ws = (char*)d_ws;
    unsigned* bkt  = (unsigned*)ws;
    char*     p    = ws + 4ull * NBKT * CAP;
    int*      gcur = (int*)p;                p += 4ull * ((NBKT + 63) & ~63);
    float*    dinv = (float*)p;              p += 4ull * N_NODES;
    unsigned* h1s  = (unsigned*)p;           p += 4ull * (size_t)N_NODES * 16;
    float*    h2s4 = (float*)p;

    const int B = 256;
    hipLaunchKernelGGL(k_init,  dim3((NBKT + B - 1) / B), dim3(B), 0, stream, gcur);
    hipLaunchKernelGGL(k_part,  dim3(NBLK_E), dim3(B), 0, stream, row, col, gcur, bkt);
    hipLaunchKernelGGL(k_deg,   dim3(NBKT),   dim3(B), 0, stream, bkt, gcur, dinv);
    hipLaunchKernelGGL(k_gemm1, dim3((N_NODES * 16 + B - 1) / B), dim3(B), 0, stream, x, W1, dinv, h1s);
    hipLaunchKernelGGL(k_conv1, dim3(NBKT),   dim3(B), 0, stream,
                       bkt, gcur, dinv, (const unsigned short*)h1s, W2, h2s4);
    hipLaunchKernelGGL(k_conv2, dim3(NBKT),   dim3(B), 0, stream, bkt, gcur, dinv, h2s4, out);
}

// Round 5
// 319.104 us; speedup vs baseline: 2.9463x; 2.9463x over previous
//
#include <hip/hip_runtime.h>
#include <hip/hip_fp16.h>

#define N_NODES 100000
#define N_EDGES 3200000
#define F_IN    128
#define F_HID   32

#define BSHIFT  7
#define BKSZ    128                               // nodes per bucket
#define NBKT    ((N_NODES + BKSZ - 1) / BKSZ)     // 782
#define CAP     4608                              // bucket capacity: mean 4092 + 8 sigma (R4-verified)
#define CHUNK   8192                              // edges per partition block
#define NBLK_E  ((N_EDGES + CHUNK - 1) / CHUNK)   // 391
#define RBITS   17                                // row id bits (100000 < 2^17)
#define RMASK   0x1FFFF

static __device__ __forceinline__ float lo_h(unsigned v) {
    return __half2float(__ushort_as_half((unsigned short)(v & 0xFFFFu)));
}
static __device__ __forceinline__ float hi_h(unsigned v) {
    return __half2float(__ushort_as_half((unsigned short)(v >> 16)));
}

// ---------------- coarse partition (fixed-capacity buckets) ----------------

__global__ __launch_bounds__(256) void k_init(int* __restrict__ gcur) {
    int i = blockIdx.x * 256 + threadIdx.x;
    if (i < NBKT) gcur[i] = i * CAP;
}

// packed word = r | (c&127)<<17
__global__ __launch_bounds__(256) void k_part(const int* __restrict__ row, const int* __restrict__ col,
                                              int* __restrict__ gcur, unsigned* __restrict__ bkt) {
    __shared__ int hist[NBKT];
    __shared__ int base[NBKT];
    int t = threadIdx.x;
    for (int i = t; i < NBKT; i += 256) hist[i] = 0;
    __syncthreads();
    int e0 = blockIdx.x * CHUNK;
    int n  = min(CHUNK, N_EDGES - e0);
    for (int i = t; i < n; i += 256) atomicAdd(&hist[col[e0 + i] >> BSHIFT], 1);
    __syncthreads();
    for (int i = t; i < NBKT; i += 256) {
        int h = hist[i];
        base[i] = h ? atomicAdd(&gcur[i], h) : 0;
    }
    __syncthreads();
    for (int i = t; i < NBKT; i += 256) hist[i] = 0;
    __syncthreads();
    for (int i = t; i < n; i += 256) {
        int c = col[e0 + i];   // L2 hit (second read)
        int b = c >> BSHIFT;
        int p = base[b] + atomicAdd(&hist[b], 1);
        bkt[p] = (unsigned)row[e0 + i] | ((unsigned)(c & (BKSZ - 1)) << RBITS);
    }
}

// ---------------- per-bucket fine sort, IN PLACE (LDS staging), + off/end/dinv ----------------

__global__ __launch_bounds__(256) void k_bucket(unsigned* __restrict__ bkt,  // in: bkt, out: srt (aliased)
                                                const int* __restrict__ gcur,
                                                int* __restrict__ off, int* __restrict__ end,
                                                float* __restrict__ dinv) {
    __shared__ unsigned stg[CAP];   // 18.4 KB staging
    __shared__ int cnt[BKSZ];
    __shared__ int cur[BKSZ];
    __shared__ int wtot[2];
    int t = threadIdx.x, b = blockIdx.x;
    int s = b * CAP, e = gcur[b], m = e - s;
    if (t < BKSZ) cnt[t] = 0;
    __syncthreads();
    for (int i = t; i < m; i += 256) {
        unsigned x = bkt[s + i];
        stg[i] = x;
        atomicAdd(&cnt[x >> RBITS], 1);
    }
    __syncthreads();

    int lane = t & 63, wid = t >> 6;
    int v = 0, incl = 0;
    if (t < BKSZ) {             // waves 0,1 fully active
        v = cnt[t];
        incl = v;
        #pragma unroll
        for (int sh = 1; sh < 64; sh <<= 1) {
            int u = __shfl_up(incl, sh);
            if (lane >= sh) incl += u;
        }
        if (lane == 63) wtot[wid] = incl;
    }
    __syncthreads();
    if (t < BKSZ) {
        int wpre = (wid == 1) ? wtot[0] : 0;
        int excl = wpre + incl - v;
        cur[t] = s + excl;
        int g = b * BKSZ + t;
        if (g < N_NODES) {
            off[g]  = s + excl;
            end[g]  = s + excl + v;
            dinv[g] = rsqrtf((float)(v + 1));   // +1 self-loop
        }
    }
    __syncthreads();
    for (int i = t; i < m; i += 256) {
        unsigned x = stg[i];
        int p = atomicAdd(&cur[x >> RBITS], 1);
        bkt[p] = x & RMASK;   // srt: row ids, grouped by dest, bucket-aligned
    }
}

// ---------------- h1s = fp16( dinv[r] * (x @ W1)[r] ), 2 feats per u32 ----------------

__global__ __launch_bounds__(256) void k_gemm1(const float* __restrict__ x, const float* __restrict__ W1,
                                               const float* __restrict__ dinv, unsigned* __restrict__ h1s) {
    __shared__ float Wlds[F_IN * F_HID];  // 16 KB, [k][f]
    int t = threadIdx.x;
    for (int i = t; i < F_IN * F_HID; i += 256) Wlds[i] = W1[i];
    __syncthreads();

    int gid = blockIdx.x * 256 + t;   // gid = r*16 + f2
    int r = gid >> 4, f2 = gid & 15;
    if (r >= N_NODES) return;

    const float4* x4 = (const float4*)(x + (size_t)r * F_IN);
    float a0 = 0.0f, a1 = 0.0f;
    int fa = 2 * f2, fb = 2 * f2 + 1;
#pragma unroll
    for (int k = 0; k < F_IN / 4; k++) {
        float4 xv = x4[k];
        a0 += xv.x * Wlds[(4 * k + 0) * F_HID + fa] + xv.y * Wlds[(4 * k + 1) * F_HID + fa]
            + xv.z * Wlds[(4 * k + 2) * F_HID + fa] + xv.w * Wlds[(4 * k + 3) * F_HID + fa];
        a1 += xv.x * Wlds[(4 * k + 0) * F_HID + fb] + xv.y * Wlds[(4 * k + 1) * F_HID + fb]
            + xv.z * Wlds[(4 * k + 2) * F_HID + fb] + xv.w * Wlds[(4 * k + 3) * F_HID + fb];
    }
    float di = dinv[r];
    unsigned s0 = (unsigned)__half_as_ushort(__float2half(di * a0));
    unsigned s1 = (unsigned)__half_as_ushort(__float2half(di * a1));
    h1s[gid] = s0 | (s1 << 16);
}

// ---------------- conv1: one wave per dest node, 4 edges in flight, register accum ----------------
// h2s4[c*4+j] = dinv[c] * (tanh(dinv[c]*(Σ_nb h1s[r] + h1s[c])) @ W2)[j]

__global__ __launch_bounds__(256) void k_conv1(const int* __restrict__ off, const int* __restrict__ end,
                                               const int* __restrict__ srt, const float* __restrict__ dinv,
                                               const unsigned* __restrict__ h1s,
                                               const float* __restrict__ W2, float* __restrict__ h2s4) {
    int wid  = threadIdx.x >> 6;
    int lane = threadIdx.x & 63;
    int c = blockIdx.x * 4 + wid;
    if (c >= N_NODES) return;
    int f2 = lane & 15;     // feature pair
    int q  = lane >> 4;     // quarter-wave -> edge slot (4 edges/iter)

    int b = off[c], e = end[c];
    float a0 = 0.0f, a1 = 0.0f;
    for (int p = b + q; p < e; p += 4) {
        int r = srt[p];                            // broadcast within quarter-wave
        unsigned v = h1s[(size_t)r * 16 + f2];     // 64B contiguous per edge
        a0 += lo_h(v);
        a1 += hi_h(v);
    }
    a0 += __shfl_xor(a0, 16); a0 += __shfl_xor(a0, 32);
    a1 += __shfl_xor(a1, 16); a1 += __shfl_xor(a1, 32);

    float di = dinv[c];
    unsigned sv = h1s[(size_t)c * 16 + f2];        // self-loop term (already dinv[c]-scaled)
    float hid0 = tanhf(di * (a0 + lo_h(sv)));
    float hid1 = tanhf(di * (a1 + hi_h(sv)));

    int fa = 2 * f2, fb = fa + 1;
    float p0 = hid0 * W2[fa * 3 + 0] + hid1 * W2[fb * 3 + 0];
    float p1 = hid0 * W2[fa * 3 + 1] + hid1 * W2[fb * 3 + 1];
    float p2 = hid0 * W2[fa * 3 + 2] + hid1 * W2[fb * 3 + 2];
#pragma unroll
    for (int m = 1; m <= 8; m <<= 1) {  // reduce over the 16 f2 lanes
        p0 += __shfl_xor(p0, m);
        p1 += __shfl_xor(p1, m);
        p2 += __shfl_xor(p2, m);
    }
    if (lane < 3) {
        float v = (lane == 0) ? p0 : (lane == 1) ? p1 : p2;
        h2s4[(size_t)c * 4 + lane] = di * v;       // pre-scaled for conv2
    }
}

// ---------------- conv2: one wave per dest node, 16 edges in flight ----------------

__global__ __launch_bounds__(256) void k_conv2(const int* __restrict__ off, const int* __restrict__ end,
                                               const int* __restrict__ srt, const float* __restrict__ dinv,
                                               const float* __restrict__ h2s4, float* __restrict__ out) {
    int wid  = threadIdx.x >> 6;
    int lane = threadIdx.x & 63;
    int c = blockIdx.x * 4 + wid;
    if (c >= N_NODES) return;
    int tm = lane >> 2, j = lane & 3;   // 16 teams of 4 lanes

    int b = off[c], e = end[c];
    float acc = 0.0f;
    for (int p = b + tm; p < e; p += 16) {
        int r = srt[p];
        if (j < 3) acc += h2s4[(size_t)r * 4 + j];
    }
#pragma unroll
    for (int m = 32; m >= 4; m >>= 1) acc += __shfl_xor(acc, m);

    float di = dinv[c];
    if (lane < 3) out[(size_t)c * 3 + lane] = di * (acc + h2s4[(size_t)c * 4 + lane]);
}

// ---------------- launch ----------------

extern "C" void kernel_launch(void* const* d_in, const int* in_sizes, int n_in,
                              void* d_out, int out_size, void* d_ws, size_t ws_size,
                              hipStream_t stream) {
    const float* x   = (const float*)d_in[0];
    const int*   ei  = (const int*)d_in[1];  // [2, E] int32
    const float* W1  = (const float*)d_in[2];
    const float* W2  = (const float*)d_in[3];
    float*       out = (float*)d_out;

    const int* row = ei;
    const int* col = ei + N_EDGES;

    // workspace:
    //  bkt/srt (aliased, in-place fine sort) : NBKT*CAP u32 = 14.41 MB
    //  gcur : NBKT | off,end : N | dinv : N  = 1.21 MB
    //  h1s  : N*16 u32                       = 6.40 MB
    //  h2s4 : N*4 f32                        = 1.60 MB
    // total ~23.6 MB (< 27.6 MB proven in R3)
    char* ws = (char*)d_ws;
    unsigned* bkt = (unsigned*)ws;
    int*      srt = (int*)ws;                 // alias (in-place after k_bucket)
    char*     p   = ws + 4ull * NBKT * CAP;
    int*      gcur = (int*)p;                 p += 4ull * ((NBKT + 63) & ~63);
    int*      off  = (int*)p;                 p += 4ull * N_NODES;
    int*      end  = (int*)p;                 p += 4ull * N_NODES;
    float*    dinv = (float*)p;               p += 4ull * N_NODES;
    unsigned* h1s  = (unsigned*)p;            p += 64ull * N_NODES;
    float*    h2s4 = (float*)p;

    const int B = 256;
    hipLaunchKernelGGL(k_init,   dim3((NBKT + B - 1) / B), dim3(B), 0, stream, gcur);
    hipLaunchKernelGGL(k_part,   dim3(NBLK_E), dim3(B), 0, stream, row, col, gcur, bkt);
    hipLaunchKernelGGL(k_bucket, dim3(NBKT),   dim3(B), 0, stream, bkt, gcur, off, end, dinv);
    hipLaunchKernelGGL(k_gemm1,  dim3((N_NODES * 16 + B - 1) / B), dim3(B), 0, stream, x, W1, dinv, h1s);
    hipLaunchKernelGGL(k_conv1,  dim3((N_NODES + 3) / 4), dim3(B), 0, stream,
                       off, end, srt, dinv, h1s, W2, h2s4);
    hipLaunchKernelGGL(k_conv2,  dim3((N_NODES + 3) / 4), dim3(B), 0, stream,
                       off, end, srt, dinv, h2s4, out);
}

// Round 6
// 297.705 us; speedup vs baseline: 3.1581x; 1.0719x over previous
//
#include <hip/hip_runtime.h>
#include <hip/hip_fp16.h>

#define N_NODES 100000
#define N_EDGES 3200000
#define F_IN    128
#define F_HID   32

#define BSHIFT  7
#define BKSZ    128                               // nodes per bucket
#define NBKT    ((N_NODES + BKSZ - 1) / BKSZ)     // 782
#define CAP     4608                              // bucket capacity: mean 4092 + 8 sigma
#define CHUNK   4096                              // edges per partition block (16/thread reg staging)
#define NBLK_E  ((N_EDGES + CHUNK - 1) / CHUNK)   // 782
#define RBITS   17                                // row id bits (100000 < 2^17)
#define RMASK   0x1FFFF

static __device__ __forceinline__ float lo_h(unsigned v) {
    return __half2float(__ushort_as_half((unsigned short)(v & 0xFFFFu)));
}
static __device__ __forceinline__ float hi_h(unsigned v) {
    return __half2float(__ushort_as_half((unsigned short)(v >> 16)));
}

// ---------------- coarse partition (fixed-capacity buckets) ----------------

__global__ __launch_bounds__(256) void k_init(int* __restrict__ gcur) {
    int i = blockIdx.x * 256 + threadIdx.x;
    if (i < NBKT) gcur[i] = i * CAP;
}

// packed word = r | (c&127)<<17 ; edges register-staged so col is read once
__global__ __launch_bounds__(256) void k_part(const int* __restrict__ row, const int* __restrict__ col,
                                              int* __restrict__ gcur, unsigned* __restrict__ bkt) {
    __shared__ int hist[NBKT];
    __shared__ int base[NBKT];
    int t = threadIdx.x;
    for (int i = t; i < NBKT; i += 256) hist[i] = 0;
    __syncthreads();

    int e0 = blockIdx.x * CHUNK;
    int n  = min(CHUNK, N_EDGES - e0);
    int r[16], c[16];
#pragma unroll
    for (int k = 0; k < 16; k++) {
        int idx = t + k * 256;
        if (idx < n) {
            r[k] = row[e0 + idx];
            c[k] = col[e0 + idx];
            atomicAdd(&hist[c[k] >> BSHIFT], 1);
        }
    }
    __syncthreads();
    for (int i = t; i < NBKT; i += 256) {
        int h = hist[i];
        base[i] = h ? atomicAdd(&gcur[i], h) : 0;
    }
    __syncthreads();
    for (int i = t; i < NBKT; i += 256) hist[i] = 0;
    __syncthreads();
#pragma unroll
    for (int k = 0; k < 16; k++) {
        int idx = t + k * 256;
        if (idx < n) {
            int b = c[k] >> BSHIFT;
            int p = base[b] + atomicAdd(&hist[b], 1);
            bkt[p] = (unsigned)r[k] | ((unsigned)(c[k] & (BKSZ - 1)) << RBITS);
        }
    }
}

// ---------------- per-bucket fine sort, IN PLACE (LDS staging), + off/end/dinv ----------------

__global__ __launch_bounds__(256) void k_bucket(unsigned* __restrict__ bkt,  // in: bkt, out: srt (aliased)
                                                const int* __restrict__ gcur,
                                                int* __restrict__ off, int* __restrict__ end,
                                                float* __restrict__ dinv) {
    __shared__ unsigned stg[CAP];   // 18.4 KB staging
    __shared__ int cnt[BKSZ];
    __shared__ int cur[BKSZ];
    __shared__ int wtot[2];
    int t = threadIdx.x, b = blockIdx.x;
    int s = b * CAP, e = gcur[b], m = e - s;
    if (t < BKSZ) cnt[t] = 0;
    __syncthreads();
    for (int i = t; i < m; i += 256) {
        unsigned x = bkt[s + i];
        stg[i] = x;
        atomicAdd(&cnt[x >> RBITS], 1);
    }
    __syncthreads();

    int lane = t & 63, wid = t >> 6;
    int v = 0, incl = 0;
    if (t < BKSZ) {             // waves 0,1 fully active
        v = cnt[t];
        incl = v;
        #pragma unroll
        for (int sh = 1; sh < 64; sh <<= 1) {
            int u = __shfl_up(incl, sh);
            if (lane >= sh) incl += u;
        }
        if (lane == 63) wtot[wid] = incl;
    }
    __syncthreads();
    if (t < BKSZ) {
        int wpre = (wid == 1) ? wtot[0] : 0;
        int excl = wpre + incl - v;
        cur[t] = s + excl;
        int g = b * BKSZ + t;
        if (g < N_NODES) {
            off[g]  = s + excl;
            end[g]  = s + excl + v;
            dinv[g] = rsqrtf((float)(v + 1));   // +1 self-loop
        }
    }
    __syncthreads();
    for (int i = t; i < m; i += 256) {
        unsigned x = stg[i];
        int p = atomicAdd(&cur[x >> RBITS], 1);
        bkt[p] = x & RMASK;   // srt: row ids grouped by dest node
    }
}

// ---------------- h1s = fp16( dinv[r] * (x @ W1)[r] ), 2 feats per u32 ----------------

__global__ __launch_bounds__(256) void k_gemm1(const float* __restrict__ x, const float* __restrict__ W1,
                                               const float* __restrict__ dinv, unsigned* __restrict__ h1s) {
    __shared__ float Wlds[F_IN * F_HID];  // 16 KB, [k][f]
    int t = threadIdx.x;
    for (int i = t; i < F_IN * F_HID; i += 256) Wlds[i] = W1[i];
    __syncthreads();

    int gid = blockIdx.x * 256 + t;   // gid = r*16 + f2
    int r = gid >> 4, f2 = gid & 15;
    if (r >= N_NODES) return;

    const float4* x4 = (const float4*)(x + (size_t)r * F_IN);
    float a0 = 0.0f, a1 = 0.0f;
    int fa = 2 * f2, fb = 2 * f2 + 1;
#pragma unroll
    for (int k = 0; k < F_IN / 4; k++) {
        float4 xv = x4[k];
        a0 += xv.x * Wlds[(4 * k + 0) * F_HID + fa] + xv.y * Wlds[(4 * k + 1) * F_HID + fa]
            + xv.z * Wlds[(4 * k + 2) * F_HID + fa] + xv.w * Wlds[(4 * k + 3) * F_HID + fa];
        a1 += xv.x * Wlds[(4 * k + 0) * F_HID + fb] + xv.y * Wlds[(4 * k + 1) * F_HID + fb]
            + xv.z * Wlds[(4 * k + 2) * F_HID + fb] + xv.w * Wlds[(4 * k + 3) * F_HID + fb];
    }
    float di = dinv[r];
    unsigned s0 = (unsigned)__half_as_ushort(__float2half(di * a0));
    unsigned s1 = (unsigned)__half_as_ushort(__float2half(di * a1));
    h1s[gid] = s0 | (s1 << 16);
}

// ---------------- conv1: one wave per dest node, 8 edges in flight (uint2 loads) ----------------
// h2s4[c*4+j] = dinv[c] * (tanh(dinv[c]*(Σ_nb h1s[r] + h1s[c])) @ W2)[j], slot 3 = 0

__global__ __launch_bounds__(256) void k_conv1(const int* __restrict__ off, const int* __restrict__ end,
                                               const int* __restrict__ srt, const float* __restrict__ dinv,
                                               const unsigned* __restrict__ h1s,
                                               const float* __restrict__ W2, float* __restrict__ h2s4) {
    int wid  = threadIdx.x >> 6;
    int lane = threadIdx.x & 63;
    int c = blockIdx.x * 4 + wid;
    if (c >= N_NODES) return;
    int o = lane & 7;       // feat-quad: feats [4o, 4o+4)
    int q = lane >> 3;      // edge slot (8 edges/iter)

    // preload W2 rows 4o..4o+3 (12 floats)
    float w00 = W2[(4*o+0)*3+0], w01 = W2[(4*o+0)*3+1], w02 = W2[(4*o+0)*3+2];
    float w10 = W2[(4*o+1)*3+0], w11 = W2[(4*o+1)*3+1], w12 = W2[(4*o+1)*3+2];
    float w20 = W2[(4*o+2)*3+0], w21 = W2[(4*o+2)*3+1], w22 = W2[(4*o+2)*3+2];
    float w30 = W2[(4*o+3)*3+0], w31 = W2[(4*o+3)*3+1], w32 = W2[(4*o+3)*3+2];

    int b = off[c], e = end[c];
    float a0 = 0.0f, a1 = 0.0f, a2 = 0.0f, a3 = 0.0f;
    const uint2* h1v = (const uint2*)h1s;
    for (int p = b + q; p < e; p += 8) {
        int r = srt[p];                         // 8 consecutive addrs per wave
        uint2 v = h1v[(size_t)r * 8 + o];       // 64B contiguous per edge
        a0 += lo_h(v.x); a1 += hi_h(v.x);
        a2 += lo_h(v.y); a3 += hi_h(v.y);
    }
#pragma unroll
    for (int m = 8; m <= 32; m <<= 1) {         // reduce over the 8 edge slots
        a0 += __shfl_xor(a0, m); a1 += __shfl_xor(a1, m);
        a2 += __shfl_xor(a2, m); a3 += __shfl_xor(a3, m);
    }

    float di = dinv[c];
    uint2 sv = h1v[(size_t)c * 8 + o];          // self term (already dinv[c]-scaled)
    float h0 = tanhf(di * (a0 + lo_h(sv.x)));
    float h1 = tanhf(di * (a1 + hi_h(sv.x)));
    float h2 = tanhf(di * (a2 + lo_h(sv.y)));
    float h3 = tanhf(di * (a3 + hi_h(sv.y)));

    float p0 = h0 * w00 + h1 * w10 + h2 * w20 + h3 * w30;
    float p1 = h0 * w01 + h1 * w11 + h2 * w21 + h3 * w31;
    float p2 = h0 * w02 + h1 * w12 + h2 * w22 + h3 * w32;
#pragma unroll
    for (int m = 1; m <= 4; m <<= 1) {          // reduce over the 8 feat-quads
        p0 += __shfl_xor(p0, m);
        p1 += __shfl_xor(p1, m);
        p2 += __shfl_xor(p2, m);
    }
    if (lane < 4) {
        float v = (lane == 0) ? p0 : (lane == 1) ? p1 : (lane == 2) ? p2 : 0.0f;
        h2s4[(size_t)c * 4 + lane] = (lane < 3) ? di * v : 0.0f;  // slot 3 = real 0 for float4 reads
    }
}

// ---------------- conv2: one wave per dest node, 64 edges in flight (float4 loads) ----------------

__global__ __launch_bounds__(256) void k_conv2(const int* __restrict__ off, const int* __restrict__ end,
                                               const int* __restrict__ srt, const float* __restrict__ dinv,
                                               const float* __restrict__ h2s4, float* __restrict__ out) {
    int wid  = threadIdx.x >> 6;
    int lane = threadIdx.x & 63;
    int c = blockIdx.x * 4 + wid;
    if (c >= N_NODES) return;

    const float4* h2v = (const float4*)h2s4;
    int b = off[c], e = end[c];
    float ax = 0.0f, ay = 0.0f, az = 0.0f;
    for (int p = b + lane; p < e; p += 64) {
        int r = srt[p];                 // coalesced 256B per wave
        float4 v = h2v[r];              // 16B per lane, 64 in flight
        ax += v.x; ay += v.y; az += v.z;
    }
#pragma unroll
    for (int m = 1; m <= 32; m <<= 1) {
        ax += __shfl_xor(ax, m);
        ay += __shfl_xor(ay, m);
        az += __shfl_xor(az, m);
    }

    float di = dinv[c];
    if (lane < 3) {
        float a = (lane == 0) ? ax : (lane == 1) ? ay : az;
        out[(size_t)c * 3 + lane] = di * (a + h2s4[(size_t)c * 4 + lane]);
    }
}

// ---------------- launch ----------------

extern "C" void kernel_launch(void* const* d_in, const int* in_sizes, int n_in,
                              void* d_out, int out_size, void* d_ws, size_t ws_size,
                              hipStream_t stream) {
    const float* x   = (const float*)d_in[0];
    const int*   ei  = (const int*)d_in[1];  // [2, E] int32
    const float* W1  = (const float*)d_in[2];
    const float* W2  = (const float*)d_in[3];
    float*       out = (float*)d_out;

    const int* row = ei;
    const int* col = ei + N_EDGES;

    // workspace (~23.6 MB, < 27.6 MB proven):
    //  bkt/srt (aliased) : NBKT*CAP u32 = 14.41 MB
    //  gcur | off,end | dinv            = 1.21 MB
    //  h1s : N*16 u32                   = 6.40 MB
    //  h2s4: N*4 f32                    = 1.60 MB
    char* ws = (char*)d_ws;
    unsigned* bkt = (unsigned*)ws;
    int*      srt = (int*)ws;                 // alias (in-place after k_bucket)
    char*     p   = ws + 4ull * NBKT * CAP;
    int*      gcur = (int*)p;                 p += 4ull * ((NBKT + 63) & ~63);
    int*      off  = (int*)p;                 p += 4ull * N_NODES;
    int*      end  = (int*)p;                 p += 4ull * N_NODES;
    float*    dinv = (float*)p;               p += 4ull * N_NODES;
    unsigned* h1s  = (unsigned*)p;            p += 64ull * N_NODES;
    float*    h2s4 = (float*)p;

    const int B = 256;
    hipLaunchKernelGGL(k_init,   dim3((NBKT + B - 1) / B), dim3(B), 0, stream, gcur);
    hipLaunchKernelGGL(k_part,   dim3(NBLK_E), dim3(B), 0, stream, row, col, gcur, bkt);
    hipLaunchKernelGGL(k_bucket, dim3(NBKT),   dim3(B), 0, stream, bkt, gcur, off, end, dinv);
    hipLaunchKernelGGL(k_gemm1,  dim3((N_NODES * 16 + B - 1) / B), dim3(B), 0, stream, x, W1, dinv, h1s);
    hipLaunchKernelGGL(k_conv1,  dim3((N_NODES + 3) / 4), dim3(B), 0, stream,
                       off, end, srt, dinv, h1s, W2, h2s4);
    hipLaunchKernelGGL(k_conv2,  dim3((N_NODES + 3) / 4), dim3(B), 0, stream,
                       off, end, srt, dinv, h2s4, out);
}

// Round 7
// 274.390 us; speedup vs baseline: 3.4264x; 1.0850x over previous
//
#include <hip/hip_runtime.h>
#include <hip/hip_fp16.h>

#define N_NODES 100000
#define N_EDGES 3200000
#define F_IN    128
#define F_HID   32

#define BSHIFT  7
#define BKSZ    128                               // nodes per bucket
#define NBKT    ((N_NODES + BKSZ - 1) / BKSZ)     // 782
#define CAP     4608                              // bucket capacity: mean 4092 + 8 sigma
#define CHUNK   4096                              // edges per partition block (16/thread reg staging)
#define NBLK_E  ((N_EDGES + CHUNK - 1) / CHUNK)   // 782
#define RBITS   17                                // row id bits (100000 < 2^17)
#define RMASK   0x1FFFF

static __device__ __forceinline__ float lo_h(unsigned v) {
    return __half2float(__ushort_as_half((unsigned short)(v & 0xFFFFu)));
}
static __device__ __forceinline__ float hi_h(unsigned v) {
    return __half2float(__ushort_as_half((unsigned short)(v >> 16)));
}

// ---------------- coarse partition (fixed-capacity buckets) ----------------

__global__ __launch_bounds__(256) void k_init(int* __restrict__ gcur) {
    int i = blockIdx.x * 256 + threadIdx.x;
    if (i < NBKT) gcur[i] = i * CAP;
}

// packed word = r | (c&127)<<17
// LDS-reorder partition: edges are permuted into bucket-major order in LDS first,
// so the global scatter becomes runs of consecutive addresses (R2/R6 lesson:
// per-edge random 4B writes cost a 32B sector each ~= 100 MB; runs coalesce).
__global__ __launch_bounds__(256) void k_part(const int* __restrict__ row, const int* __restrict__ col,
                                              int* __restrict__ gcur, unsigned* __restrict__ bkt) {
    __shared__ int hist[NBKT];
    __shared__ int lbase[NBKT];          // local (block) exclusive prefix
    __shared__ int gbase[NBKT];          // global destination base
    __shared__ unsigned perm[CHUNK];     // 16 KB: packed words, bucket-major
    __shared__ unsigned short pb[CHUNK]; // 8 KB: bucket id per slot
    __shared__ int wt[4];
    int t = threadIdx.x;
    for (int i = t; i < NBKT; i += 256) hist[i] = 0;
    __syncthreads();

    int e0 = blockIdx.x * CHUNK;
    int n  = min(CHUNK, N_EDGES - e0);
    int r[16], c[16], rk[16];
#pragma unroll
    for (int k = 0; k < 16; k++) {
        int idx = t + k * 256;
        if (idx < n) {
            r[k]  = row[e0 + idx];
            c[k]  = col[e0 + idx];
            rk[k] = atomicAdd(&hist[c[k] >> BSHIFT], 1);   // local rank in bucket
        }
    }
    __syncthreads();

    // block scan: each thread owns 4 consecutive buckets (782 <= 1024)
    {
        int b0 = t * 4;
        int s0 = (b0     < NBKT) ? hist[b0]     : 0;
        int s1 = (b0 + 1 < NBKT) ? hist[b0 + 1] : 0;
        int s2 = (b0 + 2 < NBKT) ? hist[b0 + 2] : 0;
        int s3 = (b0 + 3 < NBKT) ? hist[b0 + 3] : 0;
        int tsum = s0 + s1 + s2 + s3;
        int lane = t & 63, wid = t >> 6;
        int incl = tsum;
#pragma unroll
        for (int sh = 1; sh < 64; sh <<= 1) {
            int u = __shfl_up(incl, sh);
            if (lane >= sh) incl += u;
        }
        if (lane == 63) wt[wid] = incl;
        __syncthreads();
        int wpre = 0;
        for (int w = 0; w < wid; w++) wpre += wt[w];
        int excl = wpre + incl - tsum;
        if (b0     < NBKT) lbase[b0]     = excl;
        if (b0 + 1 < NBKT) lbase[b0 + 1] = excl + s0;
        if (b0 + 2 < NBKT) lbase[b0 + 2] = excl + s0 + s1;
        if (b0 + 3 < NBKT) lbase[b0 + 3] = excl + s0 + s1 + s2;
    }
    // reserve global space per bucket
    for (int i = t; i < NBKT; i += 256) {
        int h = hist[i];
        gbase[i] = h ? atomicAdd(&gcur[i], h) : 0;
    }
    __syncthreads();

    // permute into LDS, bucket-major
#pragma unroll
    for (int k = 0; k < 16; k++) {
        int idx = t + k * 256;
        if (idx < n) {
            int b   = c[k] >> BSHIFT;
            int pos = lbase[b] + rk[k];
            perm[pos] = (unsigned)r[k] | ((unsigned)(c[k] & (BKSZ - 1)) << RBITS);
            pb[pos]   = (unsigned short)b;
        }
    }
    __syncthreads();

    // write out: consecutive lanes -> consecutive addresses within each bucket run
    for (int i = t; i < n; i += 256) {
        int b = pb[i];
        bkt[gbase[b] + (i - lbase[b])] = perm[i];
    }
}

// ---------------- per-bucket fine sort, IN PLACE (LDS staging), + off/end/dinv ----------------

__global__ __launch_bounds__(256) void k_bucket(unsigned* __restrict__ bkt,  // in: bkt, out: srt (aliased)
                                                const int* __restrict__ gcur,
                                                int* __restrict__ off, int* __restrict__ end,
                                                float* __restrict__ dinv) {
    __shared__ unsigned stg[CAP];   // 18.4 KB staging
    __shared__ int cnt[BKSZ];
    __shared__ int cur[BKSZ];
    __shared__ int wtot[2];
    int t = threadIdx.x, b = blockIdx.x;
    int s = b * CAP, e = gcur[b], m = e - s;
    if (t < BKSZ) cnt[t] = 0;
    __syncthreads();
    for (int i = t; i < m; i += 256) {
        unsigned x = bkt[s + i];
        stg[i] = x;
        atomicAdd(&cnt[x >> RBITS], 1);
    }
    __syncthreads();

    int lane = t & 63, wid = t >> 6;
    int v = 0, incl = 0;
    if (t < BKSZ) {             // waves 0,1 fully active
        v = cnt[t];
        incl = v;
        #pragma unroll
        for (int sh = 1; sh < 64; sh <<= 1) {
            int u = __shfl_up(incl, sh);
            if (lane >= sh) incl += u;
        }
        if (lane == 63) wtot[wid] = incl;
    }
    __syncthreads();
    if (t < BKSZ) {
        int wpre = (wid == 1) ? wtot[0] : 0;
        int excl = wpre + incl - v;
        cur[t] = s + excl;
        int g = b * BKSZ + t;
        if (g < N_NODES) {
            off[g]  = s + excl;
            end[g]  = s + excl + v;
            dinv[g] = rsqrtf((float)(v + 1));   // +1 self-loop
        }
    }
    __syncthreads();
    for (int i = t; i < m; i += 256) {
        unsigned x = stg[i];
        int p = atomicAdd(&cur[x >> RBITS], 1);
        bkt[p] = x & RMASK;   // srt: row ids grouped by dest node
    }
}

// ---------------- h1s = fp16( dinv[r] * (x @ W1)[r] ), 2 feats per u32 ----------------

__global__ __launch_bounds__(256) void k_gemm1(const float* __restrict__ x, const float* __restrict__ W1,
                                               const float* __restrict__ dinv, unsigned* __restrict__ h1s) {
    __shared__ float Wlds[F_IN * F_HID];  // 16 KB, [k][f]
    int t = threadIdx.x;
    for (int i = t; i < F_IN * F_HID; i += 256) Wlds[i] = W1[i];
    __syncthreads();

    int gid = blockIdx.x * 256 + t;   // gid = r*16 + f2
    int r = gid >> 4, f2 = gid & 15;
    if (r >= N_NODES) return;

    const float4* x4 = (const float4*)(x + (size_t)r * F_IN);
    float a0 = 0.0f, a1 = 0.0f;
    int fa = 2 * f2, fb = 2 * f2 + 1;
#pragma unroll
    for (int k = 0; k < F_IN / 4; k++) {
        float4 xv = x4[k];
        a0 += xv.x * Wlds[(4 * k + 0) * F_HID + fa] + xv.y * Wlds[(4 * k + 1) * F_HID + fa]
            + xv.z * Wlds[(4 * k + 2) * F_HID + fa] + xv.w * Wlds[(4 * k + 3) * F_HID + fa];
        a1 += xv.x * Wlds[(4 * k + 0) * F_HID + fb] + xv.y * Wlds[(4 * k + 1) * F_HID + fb]
            + xv.z * Wlds[(4 * k + 2) * F_HID + fb] + xv.w * Wlds[(4 * k + 3) * F_HID + fb];
    }
    float di = dinv[r];
    unsigned s0 = (unsigned)__half_as_ushort(__float2half(di * a0));
    unsigned s1 = (unsigned)__half_as_ushort(__float2half(di * a1));
    h1s[gid] = s0 | (s1 << 16);
}

// ---------------- conv1: one wave per dest node, 8 edges in flight (uint2 loads) ----------------
// h2s4[c*4+j] = dinv[c] * (tanh(dinv[c]*(Σ_nb h1s[r] + h1s[c])) @ W2)[j], slot 3 = 0

__global__ __launch_bounds__(256) void k_conv1(const int* __restrict__ off, const int* __restrict__ end,
                                               const int* __restrict__ srt, const float* __restrict__ dinv,
                                               const unsigned* __restrict__ h1s,
                                               const float* __restrict__ W2, float* __restrict__ h2s4) {
    int wid  = threadIdx.x >> 6;
    int lane = threadIdx.x & 63;
    int c = blockIdx.x * 4 + wid;
    if (c >= N_NODES) return;
    int o = lane & 7;       // feat-quad: feats [4o, 4o+4)
    int q = lane >> 3;      // edge slot (8 edges/iter)

    float w00 = W2[(4*o+0)*3+0], w01 = W2[(4*o+0)*3+1], w02 = W2[(4*o+0)*3+2];
    float w10 = W2[(4*o+1)*3+0], w11 = W2[(4*o+1)*3+1], w12 = W2[(4*o+1)*3+2];
    float w20 = W2[(4*o+2)*3+0], w21 = W2[(4*o+2)*3+1], w22 = W2[(4*o+2)*3+2];
    float w30 = W2[(4*o+3)*3+0], w31 = W2[(4*o+3)*3+1], w32 = W2[(4*o+3)*3+2];

    int b = off[c], e = end[c];
    float a0 = 0.0f, a1 = 0.0f, a2 = 0.0f, a3 = 0.0f;
    const uint2* h1v = (const uint2*)h1s;
    for (int p = b + q; p < e; p += 8) {
        int r = srt[p];                         // 8 consecutive addrs per wave
        uint2 v = h1v[(size_t)r * 8 + o];       // 64B contiguous per edge
        a0 += lo_h(v.x); a1 += hi_h(v.x);
        a2 += lo_h(v.y); a3 += hi_h(v.y);
    }
#pragma unroll
    for (int m = 8; m <= 32; m <<= 1) {         // reduce over the 8 edge slots
        a0 += __shfl_xor(a0, m); a1 += __shfl_xor(a1, m);
        a2 += __shfl_xor(a2, m); a3 += __shfl_xor(a3, m);
    }

    float di = dinv[c];
    uint2 sv = h1v[(size_t)c * 8 + o];          // self term (already dinv[c]-scaled)
    float h0 = tanhf(di * (a0 + lo_h(sv.x)));
    float h1 = tanhf(di * (a1 + hi_h(sv.x)));
    float h2 = tanhf(di * (a2 + lo_h(sv.y)));
    float h3 = tanhf(di * (a3 + hi_h(sv.y)));

    float p0 = h0 * w00 + h1 * w10 + h2 * w20 + h3 * w30;
    float p1 = h0 * w01 + h1 * w11 + h2 * w21 + h3 * w31;
    float p2 = h0 * w02 + h1 * w12 + h2 * w22 + h3 * w32;
#pragma unroll
    for (int m = 1; m <= 4; m <<= 1) {          // reduce over the 8 feat-quads
        p0 += __shfl_xor(p0, m);
        p1 += __shfl_xor(p1, m);
        p2 += __shfl_xor(p2, m);
    }
    if (lane < 4) {
        float v = (lane == 0) ? p0 : (lane == 1) ? p1 : (lane == 2) ? p2 : 0.0f;
        h2s4[(size_t)c * 4 + lane] = (lane < 3) ? di * v : 0.0f;  // slot 3 = real 0 for float4 reads
    }
}

// ---------------- conv2: one wave per dest node, 64 edges in flight (float4 loads) ----------------

__global__ __launch_bounds__(256) void k_conv2(const int* __restrict__ off, const int* __restrict__ end,
                                               const int* __restrict__ srt, const float* __restrict__ dinv,
                                               const float* __restrict__ h2s4, float* __restrict__ out) {
    int wid  = threadIdx.x >> 6;
    int lane = threadIdx.x & 63;
    int c = blockIdx.x * 4 + wid;
    if (c >= N_NODES) return;

    const float4* h2v = (const float4*)h2s4;
    int b = off[c], e = end[c];
    float ax = 0.0f, ay = 0.0f, az = 0.0f;
    for (int p = b + lane; p < e; p += 64) {
        int r = srt[p];                 // coalesced 256B per wave
        float4 v = h2v[r];              // 16B per lane, 64 in flight
        ax += v.x; ay += v.y; az += v.z;
    }
#pragma unroll
    for (int m = 1; m <= 32; m <<= 1) {
        ax += __shfl_xor(ax, m);
        ay += __shfl_xor(ay, m);
        az += __shfl_xor(az, m);
    }

    float di = dinv[c];
    if (lane < 3) {
        float a = (lane == 0) ? ax : (lane == 1) ? ay : az;
        out[(size_t)c * 3 + lane] = di * (a + h2s4[(size_t)c * 4 + lane]);
    }
}

// ---------------- launch ----------------

extern "C" void kernel_launch(void* const* d_in, const int* in_sizes, int n_in,
                              void* d_out, int out_size, void* d_ws, size_t ws_size,
                              hipStream_t stream) {
    const float* x   = (const float*)d_in[0];
    const int*   ei  = (const int*)d_in[1];  // [2, E] int32
    const float* W1  = (const float*)d_in[2];
    const float* W2  = (const float*)d_in[3];
    float*       out = (float*)d_out;

    const int* row = ei;
    const int* col = ei + N_EDGES;

    // workspace (~23.6 MB, < 27.6 MB proven):
    //  bkt/srt (aliased) : NBKT*CAP u32 = 14.41 MB
    //  gcur | off,end | dinv            = 1.21 MB
    //  h1s : N*16 u32                   = 6.40 MB
    //  h2s4: N*4 f32                    = 1.60 MB
    char* ws = (char*)d_ws;
    unsigned* bkt = (unsigned*)ws;
    int*      srt = (int*)ws;                 // alias (in-place after k_bucket)
    char*     p   = ws + 4ull * NBKT * CAP;
    int*      gcur = (int*)p;                 p += 4ull * ((NBKT + 63) & ~63);
    int*      off  = (int*)p;                 p += 4ull * N_NODES;
    int*      end  = (int*)p;                 p += 4ull * N_NODES;
    float*    dinv = (float*)p;               p += 4ull * N_NODES;
    unsigned* h1s  = (unsigned*)p;            p += 64ull * N_NODES;
    float*    h2s4 = (float*)p;

    const int B = 256;
    hipLaunchKernelGGL(k_init,   dim3((NBKT + B - 1) / B), dim3(B), 0, stream, gcur);
    hipLaunchKernelGGL(k_part,   dim3(NBLK_E), dim3(B), 0, stream, row, col, gcur, bkt);
    hipLaunchKernelGGL(k_bucket, dim3(NBKT),   dim3(B), 0, stream, bkt, gcur, off, end, dinv);
    hipLaunchKernelGGL(k_gemm1,  dim3((N_NODES * 16 + B - 1) / B), dim3(B), 0, stream, x, W1, dinv, h1s);
    hipLaunchKernelGGL(k_conv1,  dim3((N_NODES + 3) / 4), dim3(B), 0, stream,
                       off, end, srt, dinv, h1s, W2, h2s4);
    hipLaunchKernelGGL(k_conv2,  dim3((N_NODES + 3) / 4), dim3(B), 0, stream,
                       off, end, srt, dinv, h2s4, out);
}

// Round 9
// 262.481 us; speedup vs baseline: 3.5819x; 1.0454x over previous
//
#include <hip/hip_runtime.h>
#include <hip/hip_fp16.h>

#define N_NODES 100000
#define N_EDGES 3200000
#define F_IN    128
#define F_HID   32

#define BSHIFT  7
#define BKSZ    128                               // nodes per bucket
#define NBKT    ((N_NODES + BKSZ - 1) / BKSZ)     // 782
#define CAP     4608                              // bucket capacity: mean 4092 + 8 sigma
#define CHUNK   4096                              // edges per partition block (16/thread reg staging)
#define NBLK_E  ((N_EDGES + CHUNK - 1) / CHUNK)   // 782
#define RBITS   17                                // row id bits (100000 < 2^17)
#define RMASK   0x1FFFF

// ---------------- coarse partition (fixed-capacity buckets) ----------------

__global__ __launch_bounds__(256) void k_init(int* __restrict__ gcur) {
    int i = blockIdx.x * 256 + threadIdx.x;
    if (i < NBKT) gcur[i] = i * CAP;
}

// packed word = r | (c&127)<<17 ; LDS-reorder so the global scatter is bucket-run coalesced
__global__ __launch_bounds__(256) void k_part(const int* __restrict__ row, const int* __restrict__ col,
                                              int* __restrict__ gcur, unsigned* __restrict__ bkt) {
    __shared__ int hist[NBKT];
    __shared__ int lbase[NBKT];          // local (block) exclusive prefix
    __shared__ int gbase[NBKT];          // global destination base
    __shared__ unsigned perm[CHUNK];     // 16 KB: packed words, bucket-major
    __shared__ unsigned short pb[CHUNK]; // 8 KB: bucket id per slot
    __shared__ int wt[4];
    int t = threadIdx.x;
    for (int i = t; i < NBKT; i += 256) hist[i] = 0;
    __syncthreads();

    int e0 = blockIdx.x * CHUNK;
    int n  = min(CHUNK, N_EDGES - e0);
    int r[16], c[16], rk[16];
#pragma unroll
    for (int k = 0; k < 16; k++) {
        int idx = t + k * 256;
        if (idx < n) {
            r[k]  = row[e0 + idx];
            c[k]  = col[e0 + idx];
            rk[k] = atomicAdd(&hist[c[k] >> BSHIFT], 1);   // local rank in bucket
        }
    }
    __syncthreads();

    // block scan: each thread owns 4 consecutive buckets (782 <= 1024)
    {
        int b0 = t * 4;
        int s0 = (b0     < NBKT) ? hist[b0]     : 0;
        int s1 = (b0 + 1 < NBKT) ? hist[b0 + 1] : 0;
        int s2 = (b0 + 2 < NBKT) ? hist[b0 + 2] : 0;
        int s3 = (b0 + 3 < NBKT) ? hist[b0 + 3] : 0;
        int tsum = s0 + s1 + s2 + s3;
        int lane = t & 63, wid = t >> 6;
        int incl = tsum;
#pragma unroll
        for (int sh = 1; sh < 64; sh <<= 1) {
            int u = __shfl_up(incl, sh);
            if (lane >= sh) incl += u;
        }
        if (lane == 63) wt[wid] = incl;
        __syncthreads();
        int wpre = 0;
        for (int w = 0; w < wid; w++) wpre += wt[w];
        int excl = wpre + incl - tsum;
        if (b0     < NBKT) lbase[b0]     = excl;
        if (b0 + 1 < NBKT) lbase[b0 + 1] = excl + s0;
        if (b0 + 2 < NBKT) lbase[b0 + 2] = excl + s0 + s1;
        if (b0 + 3 < NBKT) lbase[b0 + 3] = excl + s0 + s1 + s2;
    }
    for (int i = t; i < NBKT; i += 256) {
        int h = hist[i];
        gbase[i] = h ? atomicAdd(&gcur[i], h) : 0;
    }
    __syncthreads();

#pragma unroll
    for (int k = 0; k < 16; k++) {
        int idx = t + k * 256;
        if (idx < n) {
            int b   = c[k] >> BSHIFT;
            int pos = lbase[b] + rk[k];
            perm[pos] = (unsigned)r[k] | ((unsigned)(c[k] & (BKSZ - 1)) << RBITS);
            pb[pos]   = (unsigned short)b;
        }
    }
    __syncthreads();

    for (int i = t; i < n; i += 256) {
        int b = pb[i];
        bkt[gbase[b] + (i - lbase[b])] = perm[i];
    }
}

// ---------------- per-bucket fine sort, IN PLACE (LDS staging), + off/end/dinv ----------------

__global__ __launch_bounds__(256) void k_bucket(unsigned* __restrict__ bkt,  // in: bkt, out: srt (aliased)
                                                const int* __restrict__ gcur,
                                                int* __restrict__ off, int* __restrict__ end,
                                                float* __restrict__ dinv) {
    __shared__ unsigned stg[CAP];   // 18.4 KB staging
    __shared__ int cnt[BKSZ];
    __shared__ int cur[BKSZ];
    __shared__ int wtot[2];
    int t = threadIdx.x, b = blockIdx.x;
    int s = b * CAP, e = gcur[b], m = e - s;
    if (t < BKSZ) cnt[t] = 0;
    __syncthreads();
    for (int i = t; i < m; i += 256) {
        unsigned x = bkt[s + i];
        stg[i] = x;
        atomicAdd(&cnt[x >> RBITS], 1);
    }
    __syncthreads();

    int lane = t & 63, wid = t >> 6;
    int v = 0, incl = 0;
    if (t < BKSZ) {
        v = cnt[t];
        incl = v;
        #pragma unroll
        for (int sh = 1; sh < 64; sh <<= 1) {
            int u = __shfl_up(incl, sh);
            if (lane >= sh) incl += u;
        }
        if (lane == 63) wtot[wid] = incl;
    }
    __syncthreads();
    if (t < BKSZ) {
        int wpre = (wid == 1) ? wtot[0] : 0;
        int excl = wpre + incl - v;
        cur[t] = s + excl;
        int g = b * BKSZ + t;
        if (g < N_NODES) {
            off[g]  = s + excl;
            end[g]  = s + excl + v;
            dinv[g] = rsqrtf((float)(v + 1));   // +1 self-loop
        }
    }
    __syncthreads();
    for (int i = t; i < m; i += 256) {
        unsigned x = stg[i];
        int p = atomicAdd(&cur[x >> RBITS], 1);
        bkt[p] = x & RMASK;   // srt: row ids grouped by dest node
    }
}

// ---------------- h1s = fp16( dinv[r] * (x @ W1)[r] ), 4 feats/thread, ds_read_b128 ----------------

__global__ __launch_bounds__(256) void k_gemm1(const float* __restrict__ x, const float* __restrict__ W1,
                                               const float* __restrict__ dinv, unsigned* __restrict__ h1s) {
    __shared__ float Wlds[F_IN * F_HID];  // 16 KB, [k][f] (matches W1 layout; rows 16B-aligned)
    int t = threadIdx.x;
    for (int i = t; i < F_IN * F_HID; i += 256) Wlds[i] = W1[i];
    __syncthreads();

    int gid = blockIdx.x * 256 + t;   // gid = r*8 + f4 ; feats 4f4..4f4+3
    int r = gid >> 3, f4 = gid & 7;
    if (r >= N_NODES) return;

    const float4* x4  = (const float4*)(x + (size_t)r * F_IN);
    const float4* Wl4 = (const float4*)Wlds;   // [(k)*8 + f4] -> W[k][4f4..4f4+3], 16B aligned
    float ax = 0.f, ay = 0.f, az = 0.f, aw = 0.f;
#pragma unroll
    for (int k4 = 0; k4 < F_IN / 4; k4++) {
        float4 xv = x4[k4];   // broadcast across the 8 lanes sharing this row
        float4 w0 = Wl4[(4 * k4 + 0) * 8 + f4];
        ax += xv.x * w0.x; ay += xv.x * w0.y; az += xv.x * w0.z; aw += xv.x * w0.w;
        float4 w1 = Wl4[(4 * k4 + 1) * 8 + f4];
        ax += xv.y * w1.x; ay += xv.y * w1.y; az += xv.y * w1.z; aw += xv.y * w1.w;
        float4 w2 = Wl4[(4 * k4 + 2) * 8 + f4];
        ax += xv.z * w2.x; ay += xv.z * w2.y; az += xv.z * w2.z; aw += xv.z * w2.w;
        float4 w3 = Wl4[(4 * k4 + 3) * 8 + f4];
        ax += xv.w * w3.x; ay += xv.w * w3.y; az += xv.w * w3.z; aw += xv.w * w3.w;
    }
    float di = dinv[r];
    unsigned p01 = (unsigned)__half_as_ushort(__float2half(di * ax))
                 | ((unsigned)__half_as_ushort(__float2half(di * ay)) << 16);
    unsigned p23 = (unsigned)__half_as_ushort(__float2half(di * az))
                 | ((unsigned)__half_as_ushort(__float2half(di * aw)) << 16);
    uint2 outv = make_uint2(p01, p23);
    ((uint2*)h1s)[(size_t)r * 8 + f4] = outv;   // 8B coalesced
}

// ---------------- conv1: one wave per dest node, 8 edges in flight, pk-f16 accumulation ----------------
// h2s4[c*4+j] = dinv[c] * (tanh(dinv[c]*(Σ_nb h1s[r] + h1s[c])) @ W2)[j], slot 3 = 0

__global__ __launch_bounds__(256) void k_conv1(const int* __restrict__ off, const int* __restrict__ end,
                                               const int* __restrict__ srt, const float* __restrict__ dinv,
                                               const unsigned* __restrict__ h1s,
                                               const float* __restrict__ W2, float* __restrict__ h2s4) {
    int wid  = threadIdx.x >> 6;
    int lane = threadIdx.x & 63;
    int c = blockIdx.x * 4 + wid;
    if (c >= N_NODES) return;
    int o = lane & 7;       // feat-quad: feats [4o, 4o+4)
    int q = lane >> 3;      // edge slot (8 edges/iter)
    int pp = q & 1;         // which feature pair of the quad this lane finalizes
    int fA = 4 * o + 2 * pp, fB = fA + 1;

    float wA0 = W2[fA * 3 + 0], wA1 = W2[fA * 3 + 1], wA2 = W2[fA * 3 + 2];
    float wB0 = W2[fB * 3 + 0], wB1 = W2[fB * 3 + 1], wB2 = W2[fB * 3 + 2];

    int b = off[c], e = end[c];
    __half2 s01 = __float2half2_rn(0.0f);
    __half2 s23 = __float2half2_rn(0.0f);
    const uint2* h1v = (const uint2*)h1s;
    for (int p = b + q; p < e; p += 8) {
        int r = srt[p];                         // 8 consecutive addrs per wave
        uint2 v = h1v[(size_t)r * 8 + o];       // 64B contiguous per edge
        s01 = __hadd2(s01, *(const __half2*)&v.x);   // v_pk_add_f16
        s23 = __hadd2(s23, *(const __half2*)&v.y);
    }

    // to f32, butterfly over the 8 edge slots
    float f0 = __low2float(s01), f1 = __high2float(s01);
    float f2v = __low2float(s23), f3 = __high2float(s23);
#pragma unroll
    for (int m = 8; m <= 32; m <<= 1) {
        f0  += __shfl_xor(f0, m);  f1 += __shfl_xor(f1, m);
        f2v += __shfl_xor(f2v, m); f3 += __shfl_xor(f3, m);
    }

    // self-loop term: added ONCE, after the slot reduction (R8 bug: adding it
    // per-lane before the butterfly counted it 8x)
    uint2 sv = h1v[(size_t)c * 8 + o];          // already dinv[c]-scaled
    f0  += __low2float(*(const __half2*)&sv.x);
    f1  += __high2float(*(const __half2*)&sv.x);
    f2v += __low2float(*(const __half2*)&sv.y);
    f3  += __high2float(*(const __half2*)&sv.y);

    float di = dinv[c];
    float vA = pp ? f2v : f0;
    float vB = pp ? f3  : f1;
    float hA = tanhf(di * vA);
    float hB = tanhf(di * vB);

    // each (o,pp) pair appears on exactly 4 lanes -> full butterfly sums 4x the truth
    float p0 = hA * wA0 + hB * wB0;
    float p1 = hA * wA1 + hB * wB1;
    float p2 = hA * wA2 + hB * wB2;
#pragma unroll
    for (int m = 1; m <= 32; m <<= 1) {
        p0 += __shfl_xor(p0, m);
        p1 += __shfl_xor(p1, m);
        p2 += __shfl_xor(p2, m);
    }
    if (lane < 4) {
        float vv = (lane == 0) ? p0 : (lane == 1) ? p1 : (lane == 2) ? p2 : 0.0f;
        h2s4[(size_t)c * 4 + lane] = (lane < 3) ? (di * 0.25f) * vv : 0.0f;  // slot 3 = real 0
    }
}

// ---------------- conv2: one wave per dest node, 64 edges in flight (float4 loads) ----------------

__global__ __launch_bounds__(256) void k_conv2(const int* __restrict__ off, const int* __restrict__ end,
                                               const int* __restrict__ srt, const float* __restrict__ dinv,
                                               const float* __restrict__ h2s4, float* __restrict__ out) {
    int wid  = threadIdx.x >> 6;
    int lane = threadIdx.x & 63;
    int c = blockIdx.x * 4 + wid;
    if (c >= N_NODES) return;

    const float4* h2v = (const float4*)h2s4;
    int b = off[c], e = end[c];
    float ax = 0.0f, ay = 0.0f, az = 0.0f;
    for (int p = b + lane; p < e; p += 64) {
        int r = srt[p];                 // coalesced 256B per wave
        float4 v = h2v[r];              // 16B per lane, 64 in flight
        ax += v.x; ay += v.y; az += v.z;
    }
#pragma unroll
    for (int m = 1; m <= 32; m <<= 1) {
        ax += __shfl_xor(ax, m);
        ay += __shfl_xor(ay, m);
        az += __shfl_xor(az, m);
    }

    float di = dinv[c];
    if (lane < 3) {
        float a = (lane == 0) ? ax : (lane == 1) ? ay : az;
        out[(size_t)c * 3 + lane] = di * (a + h2s4[(size_t)c * 4 + lane]);
    }
}

// ---------------- launch ----------------

extern "C" void kernel_launch(void* const* d_in, const int* in_sizes, int n_in,
                              void* d_out, int out_size, void* d_ws, size_t ws_size,
                              hipStream_t stream) {
    const float* x   = (const float*)d_in[0];
    const int*   ei  = (const int*)d_in[1];  // [2, E] int32
    const float* W1  = (const float*)d_in[2];
    const float* W2  = (const float*)d_in[3];
    float*       out = (float*)d_out;

    const int* row = ei;
    const int* col = ei + N_EDGES;

    // workspace (~23.6 MB, < 27.6 MB proven):
    //  bkt/srt (aliased) : NBKT*CAP u32 = 14.41 MB
    //  gcur | off,end | dinv            = 1.21 MB
    //  h1s : N*16 u32                   = 6.40 MB
    //  h2s4: N*4 f32                    = 1.60 MB
    char* ws = (char*)d_ws;
    unsigned* bkt = (unsigned*)ws;
    int*      srt = (int*)ws;                 // alias (in-place after k_bucket)
    char*     p   = ws + 4ull * NBKT * CAP;
    int*      gcur = (int*)p;                 p += 4ull * ((NBKT + 63) & ~63);
    int*      off  = (int*)p;                 p += 4ull * N_NODES;
    int*      end  = (int*)p;                 p += 4ull * N_NODES;
    float*    dinv = (float*)p;               p += 4ull * N_NODES;
    unsigned* h1s  = (unsigned*)p;            p += 64ull * N_NODES;
    float*    h2s4 = (float*)p;

    const int B = 256;
    hipLaunchKernelGGL(k_init,   dim3((NBKT + B - 1) / B), dim3(B), 0, stream, gcur);
    hipLaunchKernelGGL(k_part,   dim3(NBLK_E), dim3(B), 0, stream, row, col, gcur, bkt);
    hipLaunchKernelGGL(k_bucket, dim3(NBKT),   dim3(B), 0, stream, bkt, gcur, off, end, dinv);
    hipLaunchKernelGGL(k_gemm1,  dim3((N_NODES * 8 + B - 1) / B), dim3(B), 0, stream, x, W1, dinv, h1s);
    hipLaunchKernelGGL(k_conv1,  dim3((N_NODES + 3) / 4), dim3(B), 0, stream,
                       off, end, srt, dinv, h1s, W2, h2s4);
    hipLaunchKernelGGL(k_conv2,  dim3((N_NODES + 3) / 4), dim3(B), 0, stream,
                       off, end, srt, dinv, h2s4, out);
}

// Round 10
// 260.637 us; speedup vs baseline: 3.6072x; 1.0071x over previous
//
#include <hip/hip_runtime.h>
#include <hip/hip_fp16.h>

#define N_NODES 100000
#define N_EDGES 3200000
#define F_IN    128
#define F_HID   32

#define BSHIFT  7
#define BKSZ    128                               // nodes per bucket
#define NBKT    ((N_NODES + BKSZ - 1) / BKSZ)     // 782
#define CAP     4608                              // bucket capacity: mean 4092 + 8 sigma
#define CHUNK   4096                              // edges per partition block
#define NBLK_E  ((N_EDGES + CHUNK - 1) / CHUNK)   // 782
#define RBITS   17                                // row id bits (100000 < 2^17)
#define RMASK   0x1FFFF

// ---------------- coarse partition (fixed-capacity buckets, relative cursors) ----------------
// gcur[] zeroed by hipMemsetAsync; holds per-bucket edge count after k_part.

// packed word = r | (c&127)<<17 ; LDS-reorder so the global scatter is bucket-run coalesced.
// 512 threads (24 waves/CU at 782 blocks — grid-limited occupancy fix vs 256-thr/12-wave).
__global__ __launch_bounds__(512) void k_part(const int* __restrict__ row, const int* __restrict__ col,
                                              int* __restrict__ gcur, unsigned* __restrict__ bkt) {
    __shared__ int hist[NBKT];
    __shared__ int lbase[NBKT];          // local (block) exclusive prefix
    __shared__ int gbase[NBKT];          // global destination base (absolute)
    __shared__ unsigned perm[CHUNK];     // 16 KB: packed words, bucket-major
    __shared__ unsigned short pb[CHUNK]; // 8 KB: bucket id per slot
    __shared__ int wt[8];
    int t = threadIdx.x;
    for (int i = t; i < NBKT; i += 512) hist[i] = 0;
    __syncthreads();

    int e0 = blockIdx.x * CHUNK;
    int n  = min(CHUNK, N_EDGES - e0);
    int r[8], c[8], rk[8];
#pragma unroll
    for (int k = 0; k < 8; k++) {
        int idx = t + k * 512;
        if (idx < n) {
            r[k]  = row[e0 + idx];
            c[k]  = col[e0 + idx];
            rk[k] = atomicAdd(&hist[c[k] >> BSHIFT], 1);   // local rank in bucket
        }
    }
    __syncthreads();

    // block scan: each thread owns 2 consecutive buckets (782 <= 1024)
    {
        int b0 = t * 2;
        int s0 = (b0     < NBKT) ? hist[b0]     : 0;
        int s1 = (b0 + 1 < NBKT) ? hist[b0 + 1] : 0;
        int tsum = s0 + s1;
        int lane = t & 63, wid = t >> 6;
        int incl = tsum;
#pragma unroll
        for (int sh = 1; sh < 64; sh <<= 1) {
            int u = __shfl_up(incl, sh);
            if (lane >= sh) incl += u;
        }
        if (lane == 63) wt[wid] = incl;
        __syncthreads();
        int wpre = 0;
        for (int w = 0; w < wid; w++) wpre += wt[w];
        int excl = wpre + incl - tsum;
        if (b0     < NBKT) lbase[b0]     = excl;
        if (b0 + 1 < NBKT) lbase[b0 + 1] = excl + s0;
    }
    // reserve global space per bucket (relative cursor + fixed region base)
    for (int i = t; i < NBKT; i += 512) {
        int h = hist[i];
        gbase[i] = i * CAP + (h ? atomicAdd(&gcur[i], h) : 0);
    }
    __syncthreads();

    // permute into LDS, bucket-major
#pragma unroll
    for (int k = 0; k < 8; k++) {
        int idx = t + k * 512;
        if (idx < n) {
            int b   = c[k] >> BSHIFT;
            int pos = lbase[b] + rk[k];
            perm[pos] = (unsigned)r[k] | ((unsigned)(c[k] & (BKSZ - 1)) << RBITS);
            pb[pos]   = (unsigned short)b;
        }
    }
    __syncthreads();

    // write out: consecutive lanes -> consecutive addresses within each bucket run
    for (int i = t; i < n; i += 512) {
        int b = pb[i];
        bkt[gbase[b] + (i - lbase[b])] = perm[i];
    }
}

// ---------------- per-bucket fine sort, IN PLACE (LDS staging), + off/end/dinv ----------------
// 1024 threads: 16 waves/block, 2 resident blocks/CU = 32 waves/CU (vs 12 at 256-thr).

__global__ __launch_bounds__(1024) void k_bucket(unsigned* __restrict__ bkt,  // in: bkt, out: srt (aliased)
                                                 const int* __restrict__ gcur,
                                                 int* __restrict__ off, int* __restrict__ end,
                                                 float* __restrict__ dinv) {
    __shared__ unsigned stg[CAP];   // 18.4 KB staging
    __shared__ int cnt[BKSZ];
    __shared__ int cur[BKSZ];
    __shared__ int wtot[2];
    int t = threadIdx.x, b = blockIdx.x;
    int s = b * CAP, m = gcur[b];   // gcur now holds the bucket count
    if (t < BKSZ) cnt[t] = 0;
    __syncthreads();
    for (int i = t; i < m; i += 1024) {
        unsigned x = bkt[s + i];
        stg[i] = x;
        atomicAdd(&cnt[x >> RBITS], 1);
    }
    __syncthreads();

    int lane = t & 63, wid = t >> 6;
    int v = 0, incl = 0;
    if (t < BKSZ) {                 // waves 0,1 do the 128-counter scan
        v = cnt[t];
        incl = v;
        #pragma unroll
        for (int sh = 1; sh < 64; sh <<= 1) {
            int u = __shfl_up(incl, sh);
            if (lane >= sh) incl += u;
        }
        if (lane == 63) wtot[wid] = incl;
    }
    __syncthreads();
    if (t < BKSZ) {
        int wpre = (wid == 1) ? wtot[0] : 0;
        int excl = wpre + incl - v;
        cur[t] = s + excl;
        int g = b * BKSZ + t;
        if (g < N_NODES) {
            off[g]  = s + excl;
            end[g]  = s + excl + v;
            dinv[g] = rsqrtf((float)(v + 1));   // +1 self-loop
        }
    }
    __syncthreads();
    for (int i = t; i < m; i += 1024) {
        unsigned x = stg[i];
        int p = atomicAdd(&cur[x >> RBITS], 1);
        bkt[p] = x & RMASK;   // srt: row ids grouped by dest node
    }
}

// ---------------- h1s = fp16( dinv[r] * (x @ W1)[r] ), 4 feats/thread, ds_read_b128 ----------------

__global__ __launch_bounds__(256) void k_gemm1(const float* __restrict__ x, const float* __restrict__ W1,
                                               const float* __restrict__ dinv, unsigned* __restrict__ h1s) {
    __shared__ float Wlds[F_IN * F_HID];  // 16 KB, [k][f] (matches W1 layout; rows 16B-aligned)
    int t = threadIdx.x;
    for (int i = t; i < F_IN * F_HID; i += 256) Wlds[i] = W1[i];
    __syncthreads();

    int gid = blockIdx.x * 256 + t;   // gid = r*8 + f4 ; feats 4f4..4f4+3
    int r = gid >> 3, f4 = gid & 7;
    if (r >= N_NODES) return;

    const float4* x4  = (const float4*)(x + (size_t)r * F_IN);
    const float4* Wl4 = (const float4*)Wlds;   // [(k)*8 + f4] -> W[k][4f4..4f4+3], 16B aligned
    float ax = 0.f, ay = 0.f, az = 0.f, aw = 0.f;
#pragma unroll
    for (int k4 = 0; k4 < F_IN / 4; k4++) {
        float4 xv = x4[k4];   // broadcast across the 8 lanes sharing this row
        float4 w0 = Wl4[(4 * k4 + 0) * 8 + f4];
        ax += xv.x * w0.x; ay += xv.x * w0.y; az += xv.x * w0.z; aw += xv.x * w0.w;
        float4 w1 = Wl4[(4 * k4 + 1) * 8 + f4];
        ax += xv.y * w1.x; ay += xv.y * w1.y; az += xv.y * w1.z; aw += xv.y * w1.w;
        float4 w2 = Wl4[(4 * k4 + 2) * 8 + f4];
        ax += xv.z * w2.x; ay += xv.z * w2.y; az += xv.z * w2.z; aw += xv.z * w2.w;
        float4 w3 = Wl4[(4 * k4 + 3) * 8 + f4];
        ax += xv.w * w3.x; ay += xv.w * w3.y; az += xv.w * w3.z; aw += xv.w * w3.w;
    }
    float di = dinv[r];
    unsigned p01 = (unsigned)__half_as_ushort(__float2half(di * ax))
                 | ((unsigned)__half_as_ushort(__float2half(di * ay)) << 16);
    unsigned p23 = (unsigned)__half_as_ushort(__float2half(di * az))
                 | ((unsigned)__half_as_ushort(__float2half(di * aw)) << 16);
    uint2 outv = make_uint2(p01, p23);
    ((uint2*)h1s)[(size_t)r * 8 + f4] = outv;   // 8B coalesced
}

// ---------------- conv1: one wave per dest node, 8 edges in flight, pk-f16 accumulation ----------------
// h2s4[c*4+j] = dinv[c] * (tanh(dinv[c]*(Σ_nb h1s[r] + h1s[c])) @ W2)[j], slot 3 = 0

__global__ __launch_bounds__(256) void k_conv1(const int* __restrict__ off, const int* __restrict__ end,
                                               const int* __restrict__ srt, const float* __restrict__ dinv,
                                               const unsigned* __restrict__ h1s,
                                               const float* __restrict__ W2, float* __restrict__ h2s4) {
    int wid  = threadIdx.x >> 6;
    int lane = threadIdx.x & 63;
    int c = blockIdx.x * 4 + wid;
    if (c >= N_NODES) return;
    int o = lane & 7;       // feat-quad: feats [4o, 4o+4)
    int q = lane >> 3;      // edge slot (8 edges/iter)
    int pp = q & 1;         // which feature pair of the quad this lane finalizes
    int fA = 4 * o + 2 * pp, fB = fA + 1;

    float wA0 = W2[fA * 3 + 0], wA1 = W2[fA * 3 + 1], wA2 = W2[fA * 3 + 2];
    float wB0 = W2[fB * 3 + 0], wB1 = W2[fB * 3 + 1], wB2 = W2[fB * 3 + 2];

    int b = off[c], e = end[c];
    __half2 s01 = __float2half2_rn(0.0f);
    __half2 s23 = __float2half2_rn(0.0f);
    const uint2* h1v = (const uint2*)h1s;
    for (int p = b + q; p < e; p += 8) {
        int r = srt[p];                         // 8 consecutive addrs per wave
        uint2 v = h1v[(size_t)r * 8 + o];       // 64B contiguous per edge
        s01 = __hadd2(s01, *(const __half2*)&v.x);   // v_pk_add_f16
        s23 = __hadd2(s23, *(const __half2*)&v.y);
    }

    // to f32, butterfly over the 8 edge slots
    float f0 = __low2float(s01), f1 = __high2float(s01);
    float f2v = __low2float(s23), f3 = __high2float(s23);
#pragma unroll
    for (int m = 8; m <= 32; m <<= 1) {
        f0  += __shfl_xor(f0, m);  f1 += __shfl_xor(f1, m);
        f2v += __shfl_xor(f2v, m); f3 += __shfl_xor(f3, m);
    }

    // self-loop term: added ONCE, after the slot reduction
    uint2 sv = h1v[(size_t)c * 8 + o];          // already dinv[c]-scaled
    f0  += __low2float(*(const __half2*)&sv.x);
    f1  += __high2float(*(const __half2*)&sv.x);
    f2v += __low2float(*(const __half2*)&sv.y);
    f3  += __high2float(*(const __half2*)&sv.y);

    float di = dinv[c];
    float vA = pp ? f2v : f0;
    float vB = pp ? f3  : f1;
    float hA = tanhf(di * vA);
    float hB = tanhf(di * vB);

    // each (o,pp) pair appears on exactly 4 lanes -> full butterfly sums 4x the truth
    float p0 = hA * wA0 + hB * wB0;
    float p1 = hA * wA1 + hB * wB1;
    float p2 = hA * wA2 + hB * wB2;
#pragma unroll
    for (int m = 1; m <= 32; m <<= 1) {
        p0 += __shfl_xor(p0, m);
        p1 += __shfl_xor(p1, m);
        p2 += __shfl_xor(p2, m);
    }
    if (lane < 4) {
        float vv = (lane == 0) ? p0 : (lane == 1) ? p1 : (lane == 2) ? p2 : 0.0f;
        h2s4[(size_t)c * 4 + lane] = (lane < 3) ? (di * 0.25f) * vv : 0.0f;  // slot 3 = real 0
    }
}

// ---------------- conv2: one wave per dest node, 64 edges in flight (float4 loads) ----------------

__global__ __launch_bounds__(256) void k_conv2(const int* __restrict__ off, const int* __restrict__ end,
                                               const int* __restrict__ srt, const float* __restrict__ dinv,
                                               const float* __restrict__ h2s4, float* __restrict__ out) {
    int wid  = threadIdx.x >> 6;
    int lane = threadIdx.x & 63;
    int c = blockIdx.x * 4 + wid;
    if (c >= N_NODES) return;

    const float4* h2v = (const float4*)h2s4;
    int b = off[c], e = end[c];
    float ax = 0.0f, ay = 0.0f, az = 0.0f;
    for (int p = b + lane; p < e; p += 64) {
        int r = srt[p];                 // coalesced 256B per wave
        float4 v = h2v[r];              // 16B per lane, 64 in flight
        ax += v.x; ay += v.y; az += v.z;
    }
#pragma unroll
    for (int m = 1; m <= 32; m <<= 1) {
        ax += __shfl_xor(ax, m);
        ay += __shfl_xor(ay, m);
        az += __shfl_xor(az, m);
    }

    float di = dinv[c];
    if (lane < 3) {
        float a = (lane == 0) ? ax : (lane == 1) ? ay : az;
        out[(size_t)c * 3 + lane] = di * (a + h2s4[(size_t)c * 4 + lane]);
    }
}

// ---------------- launch ----------------

extern "C" void kernel_launch(void* const* d_in, const int* in_sizes, int n_in,
                              void* d_out, int out_size, void* d_ws, size_t ws_size,
                              hipStream_t stream) {
    const float* x   = (const float*)d_in[0];
    const int*   ei  = (const int*)d_in[1];  // [2, E] int32
    const float* W1  = (const float*)d_in[2];
    const float* W2  = (const float*)d_in[3];
    float*       out = (float*)d_out;

    const int* row = ei;
    const int* col = ei + N_EDGES;

    // workspace (~23.6 MB, < 27.6 MB proven):
    //  bkt/srt (aliased) : NBKT*CAP u32 = 14.41 MB
    //  gcur | off,end | dinv            = 1.21 MB
    //  h1s : N*16 u32                   = 6.40 MB
    //  h2s4: N*4 f32                    = 1.60 MB
    char* ws = (char*)d_ws;
    unsigned* bkt = (unsigned*)ws;
    int*      srt = (int*)ws;                 // alias (in-place after k_bucket)
    char*     p   = ws + 4ull * NBKT * CAP;
    int*      gcur = (int*)p;                 p += 4ull * ((NBKT + 63) & ~63);
    int*      off  = (int*)p;                 p += 4ull * N_NODES;
    int*      end  = (int*)p;                 p += 4ull * N_NODES;
    float*    dinv = (float*)p;               p += 4ull * N_NODES;
    unsigned* h1s  = (unsigned*)p;            p += 64ull * N_NODES;
    float*    h2s4 = (float*)p;

    const int B = 256;
    hipMemsetAsync(gcur, 0, 4ull * NBKT, stream);   // replaces k_init (relative cursors)
    hipLaunchKernelGGL(k_part,   dim3(NBLK_E), dim3(512),  0, stream, row, col, gcur, bkt);
    hipLaunchKernelGGL(k_bucket, dim3(NBKT),   dim3(1024), 0, stream, bkt, gcur, off, end, dinv);
    hipLaunchKernelGGL(k_gemm1,  dim3((N_NODES * 8 + B - 1) / B), dim3(B), 0, stream, x, W1, dinv, h1s);
    hipLaunchKernelGGL(k_conv1,  dim3((N_NODES + 3) / 4), dim3(B), 0, stream,
                       off, end, srt, dinv, h1s, W2, h2s4);
    hipLaunchKernelGGL(k_conv2,  dim3((N_NODES + 3) / 4), dim3(B), 0, stream,
                       off, end, srt, dinv, h2s4, out);
}